// Round 21
// baseline (83.623 us; speedup 1.0000x reference)
//
#include <hip/hip_runtime.h>
#include <hip/hip_bf16.h>

typedef __bf16 bf16x8 __attribute__((ext_vector_type(8)));
typedef float  f32x4  __attribute__((ext_vector_type(4)));

#define IN_F   4096
#define OUT_F  4096
#define RANK   32

__device__ __forceinline__ bf16x8 cvt8(float4 a, float4 b) {
    bf16x8 r;
    r[0] = (__bf16)a.x; r[1] = (__bf16)a.y; r[2] = (__bf16)a.z; r[3] = (__bf16)a.w;
    r[4] = (__bf16)b.x; r[5] = (__bf16)b.y; r[6] = (__bf16)b.z; r[7] = (__bf16)b.w;
    return r;
}

// ---------------- Kernel 1: Hpart[slice] = X @ V^T (bf16 partials) ----------------
// R19's proven 32-waves/CU skeleton with traffic fixed: 256 thr, (256,8),
// plain VGPR fragment loads, NO barriers anywhere. grid (128 token-blocks,
// 8 slices of 512 feats). Wave = 16 tokens x full slice x ALL 32 ranks ->
// wave-complete partial, direct bf16 global store (no LDS reduce, no S —
// S folded into hred). X read exactly once (128 MB); V re-reads = 64 MB,
// L2-resident (V = 512 KB total). Hpart bf16 = 4 MB -> 5 MB ws total,
// the SAME threshold proven taken in R12's profile (no branch ambiguity).
__global__ __launch_bounds__(256, 8)
void lora_h(const float* __restrict__ X, const float* __restrict__ V,
            __hip_bfloat16* __restrict__ Hpart)
{
    const int tid  = threadIdx.x;
    const int wave = tid >> 6;          // token 16-tile within the 64-token block
    const int lane = tid & 63;
    const int r    = lane & 15;
    const int kg   = lane >> 4;

    const int t0 = blockIdx.x * 64 + wave * 16;
    const int f0 = blockIdx.y * 512;

    const float* xrow  = X + (size_t)(t0 + r) * IN_F + f0 + kg * 8;
    const float* v0row = V + (size_t)r        * IN_F + f0 + kg * 8;
    const float* v1row = V + (size_t)(16 + r) * IN_F + f0 + kg * 8;

    f32x4 a0 = {0.f, 0.f, 0.f, 0.f};
    f32x4 a1 = {0.f, 0.f, 0.f, 0.f};

    #pragma unroll 4
    for (int s = 0; s < 16; ++s) {      // 16 K-steps x 32 feats = 512
        const float4* xp  = reinterpret_cast<const float4*>(xrow  + s * 32);
        const float4* vp0 = reinterpret_cast<const float4*>(v0row + s * 32);
        const float4* vp1 = reinterpret_cast<const float4*>(v1row + s * 32);
        float4 x0 = xp[0],  x1 = xp[1];
        float4 va = vp0[0], vb = vp0[1];
        float4 vc = vp1[0], vd = vp1[1];
        bf16x8 xb = cvt8(x0, x1);
        // A = X (m = token), B = V (n = rank-in-half)
        a0 = __builtin_amdgcn_mfma_f32_16x16x32_bf16(xb, cvt8(va, vb), a0, 0, 0, 0);
        a1 = __builtin_amdgcn_mfma_f32_16x16x32_bf16(xb, cvt8(vc, vd), a1, 0, 0, 0);
    }

    // D: token = t0 + kg*4 + j, rank = r / 16+r. Direct bf16 store.
    __hip_bfloat16* Hq = Hpart + (size_t)blockIdx.y * (8192 * RANK)
                               + (size_t)t0 * RANK;
    #pragma unroll
    for (int j = 0; j < 4; ++j) {
        const int tok = kg * 4 + j;
        Hq[(size_t)tok * RANK + r]      = (__hip_bfloat16)a0[j];
        Hq[(size_t)tok * RANK + 16 + r] = (__hip_bfloat16)a1[j];
    }
}

// ---------------- Kernel 1.5: H = (sum_k Hpart[k]) * S ----------------
// 256 blocks x 256 thr; thread handles 4 consecutive elements (rank 4-aligned).
template <int NKS>
__global__ __launch_bounds__(256)
void lora_hred(const ushort* __restrict__ Hpart, const float* __restrict__ S,
               float* __restrict__ H)
{
    const int idx = (blockIdx.x * 256 + threadIdx.x) * 4;   // element index
    const int rk  = idx & 31;

    float acc[4] = {0.f, 0.f, 0.f, 0.f};
    #pragma unroll
    for (int k = 0; k < NKS; ++k) {
        ushort4 u = *reinterpret_cast<const ushort4*>(
            Hpart + (size_t)k * (8192 * RANK) + idx);
        acc[0] += __uint_as_float((unsigned)u.x << 16);
        acc[1] += __uint_as_float((unsigned)u.y << 16);
        acc[2] += __uint_as_float((unsigned)u.z << 16);
        acc[3] += __uint_as_float((unsigned)u.w << 16);
    }
    float4 out;
    out.x = acc[0] * S[rk];
    out.y = acc[1] * S[rk + 1];
    out.z = acc[2] * S[rk + 2];
    out.w = acc[3] * S[rk + 3];
    *reinterpret_cast<float4*>(H + idx) = out;
}

// ---------------- Fallback (small ws): naive H ----------------
__global__ __launch_bounds__(256)
void lora_h_naive(const float* __restrict__ X, const float* __restrict__ S,
                  const float* __restrict__ V, float* __restrict__ H)
{
    const int idx = blockIdx.x * 256 + threadIdx.x;   // 262144 = 8192*32
    const int tok = idx >> 5, rk = idx & 31;
    float acc = 0.f;
    for (int f = 0; f < IN_F; ++f)
        acc += X[(size_t)tok * IN_F + f] * V[(size_t)rk * IN_F + f];
    H[idx] = acc * S[rk];
}

// ---------------- Kernel 2 (proven ~9.5 µs): Out = H @ U^T ----------------
__global__ __launch_bounds__(256, 4)
void lora_out(const float* __restrict__ H, const float* __restrict__ U,
              float* __restrict__ Out)
{
    __shared__ float Hs[32][33];

    const int tid  = threadIdx.x;
    const int wave = tid >> 6;
    const int lane = tid & 63;
    const int r    = lane & 15;
    const int kg   = lane >> 4;

    const int tt = blockIdx.x >> 2;
    const int cq = blockIdx.x & 3;
    const int t0 = tt * 32;

    {
        float4 v = reinterpret_cast<const float4*>(H + (size_t)t0 * RANK)[tid];
        const int tok = tid >> 3;
        const int rr  = (tid & 7) * 4;
        Hs[tok][rr] = v.x; Hs[tok][rr + 1] = v.y;
        Hs[tok][rr + 2] = v.z; Hs[tok][rr + 3] = v.w;
    }
    __syncthreads();

    bf16x8 hb[2];
    #pragma unroll
    for (int a = 0; a < 2; ++a)
        #pragma unroll
        for (int j = 0; j < 8; ++j) hb[a][j] = (__bf16)Hs[a * 16 + r][kg * 8 + j];

    const int wc0 = cq * 1024 + wave * 256;

    #pragma unroll
    for (int g = 0; g < 4; ++g) {
        float4 u0[4], u1[4];
        #pragma unroll
        for (int b = 0; b < 4; ++b) {
            const float4* up = reinterpret_cast<const float4*>(
                U + (size_t)(wc0 + g * 64 + b * 16 + r) * RANK + kg * 8);
            u0[b] = up[0];
            u1[b] = up[1];
        }
        #pragma unroll
        for (int b = 0; b < 4; ++b) {
            bf16x8 ub = cvt8(u0[b], u1[b]);
            #pragma unroll
            for (int a = 0; a < 2; ++a) {
                f32x4 d = {0.f, 0.f, 0.f, 0.f};
                d = __builtin_amdgcn_mfma_f32_16x16x32_bf16(ub, hb[a], d, 0, 0, 0);
                *reinterpret_cast<float4*>(
                    Out + (size_t)(t0 + a * 16 + r) * OUT_F
                        + wc0 + g * 64 + b * 16 + kg * 4)
                    = *reinterpret_cast<float4*>(&d);
            }
        }
    }
}

extern "C" void kernel_launch(void* const* d_in, const int* in_sizes, int n_in,
                              void* d_out, int out_size, void* d_ws, size_t ws_size,
                              hipStream_t stream) {
    const float* X = (const float*)d_in[0];
    const float* U = (const float*)d_in[1];
    const float* S = (const float*)d_in[2];
    const float* V = (const float*)d_in[3];
    float* Out = (float*)d_out;

    float* H = (float*)d_ws;                              // 1 MB fp32
    __hip_bfloat16* Hpart = (__hip_bfloat16*)((float*)d_ws + 262144);  // 4 MB bf16

    if (ws_size >= (size_t)5 * 1024 * 1024) {             // proven-available branch
        lora_h<<<dim3(128, 8), 256, 0, stream>>>(X, V, Hpart);
        lora_hred<8><<<256, 256, 0, stream>>>((const ushort*)Hpart, S, H);
        lora_out<<<1024, 256, 0, stream>>>(H, U, Out);
    } else {
        lora_h_naive<<<1024, 256, 0, stream>>>(X, S, V, H);
        lora_out<<<1024, 256, 0, stream>>>(H, U, Out);
    }
}

// Round 22
// 64.602 us; speedup vs baseline: 1.2944x; 1.2944x over previous
//
#include <hip/hip_runtime.h>
#include <hip/hip_bf16.h>

typedef __bf16 bf16x4 __attribute__((ext_vector_type(4)));
typedef __bf16 bf16x8 __attribute__((ext_vector_type(8)));
typedef float  f32x4  __attribute__((ext_vector_type(4)));

#define IN_F   4096
#define OUT_F  4096
#define RANK   32

__device__ __forceinline__ bf16x8 cvt8(float4 a, float4 b) {
    bf16x8 r;
    r[0] = (__bf16)a.x; r[1] = (__bf16)a.y; r[2] = (__bf16)a.z; r[3] = (__bf16)a.w;
    r[4] = (__bf16)b.x; r[5] = (__bf16)b.y; r[6] = (__bf16)b.z; r[7] = (__bf16)b.w;
    return r;
}
__device__ __forceinline__ bf16x4 cvt4(float4 a) {
    bf16x4 r;
    r[0] = (__bf16)a.x; r[1] = (__bf16)a.y; r[2] = (__bf16)a.z; r[3] = (__bf16)a.w;
    return r;
}

// ---------------- Kernel 1: Hpart[slice] = X @ V^T (bf16 partials) ----------------
// The never-tested cell: 2048 blocks (TRUE 8 blocks/CU, 32 waves/CU) x minimal
// traffic (X 128 MB once, V 128 MB L2-hot) x contiguous staging. 256 thr
// (4 waves = tt x rh), block = 32 tokens x 512-feat slice, 8 chunks of 64
// feats, double-buffered bf16 LDS (16.5 KB). Every stage instruction = 4
// COMPLETE rows (fully-used cache lines); fragment reads via R18-proven XOR
// swizzle. One barrier per chunk. acc = 1 f32x4/wave -> direct bf16 store.
__global__ __launch_bounds__(256, 8)
void lora_h(const float* __restrict__ X, const float* __restrict__ V,
            __hip_bfloat16* __restrict__ Hpart)
{
    __shared__ __bf16 XL[2][32 * 64];   // 8 KB  (double-buffered chunk)
    __shared__ __bf16 VL[2][32 * 64];   // 8 KB

    const int tid  = threadIdx.x;
    const int wave = tid >> 6;
    const int lane = tid & 63;
    const int r    = lane & 15;
    const int kg   = lane >> 4;

    const int tt = wave & 1;            // token 16-tile
    const int rh = wave >> 1;           // rank half

    const int t0 = blockIdx.x * 32;
    const int f0 = blockIdx.y * 512;

    // stage chunk c (64 feats): 2 contiguous float4 loads/thread for X and V;
    // each wave-instruction covers 4 complete 256 B rows. bf16-cvt + XOR-
    // swizzled LDS write (granule 8 elems = 16 B; 4-elem writes stay aligned).
    auto stage = [&](int c, int buf) {
        const int fc = f0 + c * 64;
        #pragma unroll
        for (int i = 0; i < 2; ++i) {
            const int f4   = tid + i * 256;     // float4 index 0..511
            const int row  = f4 >> 4;           // 16 float4 per 64-feat row
            const int colf = (f4 & 15) * 4;     // float col within row
            float4 xv = *reinterpret_cast<const float4*>(
                X + (size_t)(t0 + row) * IN_F + fc + colf);
            float4 vv = *reinterpret_cast<const float4*>(
                V + (size_t)row * IN_F + fc + colf);
            const int e = colf ^ ((row & 7) << 3);
            *reinterpret_cast<bf16x4*>(&XL[buf][row * 64 + e]) = cvt4(xv);
            *reinterpret_cast<bf16x4*>(&VL[buf][row * 64 + e]) = cvt4(vv);
        }
    };

    f32x4 acc = {0.f, 0.f, 0.f, 0.f};   // this wave's 16 tok x 16 ranks

    auto compute = [&](int buf) {
        const int sw = (r & 7) << 3;    // read-side swizzle (matches write)
        #pragma unroll
        for (int s = 0; s < 2; ++s) {   // 2 K-steps x 32 feats = 64
            bf16x8 xb = *reinterpret_cast<const bf16x8*>(
                &XL[buf][(tt * 16 + r) * 64 + ((s * 32 + kg * 8) ^ sw)]);
            bf16x8 vb = *reinterpret_cast<const bf16x8*>(
                &VL[buf][(rh * 16 + r) * 64 + ((s * 32 + kg * 8) ^ sw)]);
            // A = X (m = token), B = V (n = rank-in-half)
            acc = __builtin_amdgcn_mfma_f32_16x16x32_bf16(xb, vb, acc, 0, 0, 0);
        }
    };

    stage(0, 0);
    __syncthreads();

    for (int c = 0; c < 8; ++c) {
        if (c + 1 < 8) stage(c + 1, (c + 1) & 1);  // write other buffer: no race
        compute(c & 1);
        __syncthreads();                            // publish c+1, retire c
    }

    // D: token = t0 + tt*16 + kg*4 + j, rank = rh*16 + r. Direct bf16 store.
    __hip_bfloat16* Hq = Hpart + (size_t)blockIdx.y * (8192 * RANK)
                               + (size_t)(t0 + tt * 16) * RANK;
    #pragma unroll
    for (int j = 0; j < 4; ++j)
        Hq[(size_t)(kg * 4 + j) * RANK + rh * 16 + r] = (__hip_bfloat16)acc[j];
}

// ---------------- Kernel 1.5: H = (sum_k Hpart[k]) * S ----------------
template <int NKS>
__global__ __launch_bounds__(256)
void lora_hred(const ushort* __restrict__ Hpart, const float* __restrict__ S,
               float* __restrict__ H)
{
    const int idx = (blockIdx.x * 256 + threadIdx.x) * 4;   // element index
    const int rk  = idx & 31;

    float acc[4] = {0.f, 0.f, 0.f, 0.f};
    #pragma unroll
    for (int k = 0; k < NKS; ++k) {
        ushort4 u = *reinterpret_cast<const ushort4*>(
            Hpart + (size_t)k * (8192 * RANK) + idx);
        acc[0] += __uint_as_float((unsigned)u.x << 16);
        acc[1] += __uint_as_float((unsigned)u.y << 16);
        acc[2] += __uint_as_float((unsigned)u.z << 16);
        acc[3] += __uint_as_float((unsigned)u.w << 16);
    }
    float4 out;
    out.x = acc[0] * S[rk];
    out.y = acc[1] * S[rk + 1];
    out.z = acc[2] * S[rk + 2];
    out.w = acc[3] * S[rk + 3];
    *reinterpret_cast<float4*>(H + idx) = out;
}

// ---------------- Fallback (small ws): naive H ----------------
__global__ __launch_bounds__(256)
void lora_h_naive(const float* __restrict__ X, const float* __restrict__ S,
                  const float* __restrict__ V, float* __restrict__ H)
{
    const int idx = blockIdx.x * 256 + threadIdx.x;   // 262144 = 8192*32
    const int tok = idx >> 5, rk = idx & 31;
    float acc = 0.f;
    for (int f = 0; f < IN_F; ++f)
        acc += X[(size_t)tok * IN_F + f] * V[(size_t)rk * IN_F + f];
    H[idx] = acc * S[rk];
}

// ---------------- Kernel 2 (proven ~9.5 µs): Out = H @ U^T ----------------
__global__ __launch_bounds__(256, 4)
void lora_out(const float* __restrict__ H, const float* __restrict__ U,
              float* __restrict__ Out)
{
    __shared__ float Hs[32][33];

    const int tid  = threadIdx.x;
    const int wave = tid >> 6;
    const int lane = tid & 63;
    const int r    = lane & 15;
    const int kg   = lane >> 4;

    const int tt = blockIdx.x >> 2;
    const int cq = blockIdx.x & 3;
    const int t0 = tt * 32;

    {
        float4 v = reinterpret_cast<const float4*>(H + (size_t)t0 * RANK)[tid];
        const int tok = tid >> 3;
        const int rr  = (tid & 7) * 4;
        Hs[tok][rr] = v.x; Hs[tok][rr + 1] = v.y;
        Hs[tok][rr + 2] = v.z; Hs[tok][rr + 3] = v.w;
    }
    __syncthreads();

    bf16x8 hb[2];
    #pragma unroll
    for (int a = 0; a < 2; ++a)
        #pragma unroll
        for (int j = 0; j < 8; ++j) hb[a][j] = (__bf16)Hs[a * 16 + r][kg * 8 + j];

    const int wc0 = cq * 1024 + wave * 256;

    #pragma unroll
    for (int g = 0; g < 4; ++g) {
        float4 u0[4], u1[4];
        #pragma unroll
        for (int b = 0; b < 4; ++b) {
            const float4* up = reinterpret_cast<const float4*>(
                U + (size_t)(wc0 + g * 64 + b * 16 + r) * RANK + kg * 8);
            u0[b] = up[0];
            u1[b] = up[1];
        }
        #pragma unroll
        for (int b = 0; b < 4; ++b) {
            bf16x8 ub = cvt8(u0[b], u1[b]);
            #pragma unroll
            for (int a = 0; a < 2; ++a) {
                f32x4 d = {0.f, 0.f, 0.f, 0.f};
                d = __builtin_amdgcn_mfma_f32_16x16x32_bf16(ub, hb[a], d, 0, 0, 0);
                *reinterpret_cast<float4*>(
                    Out + (size_t)(t0 + a * 16 + r) * OUT_F
                        + wc0 + g * 64 + b * 16 + kg * 4)
                    = *reinterpret_cast<float4*>(&d);
            }
        }
    }
}

extern "C" void kernel_launch(void* const* d_in, const int* in_sizes, int n_in,
                              void* d_out, int out_size, void* d_ws, size_t ws_size,
                              hipStream_t stream) {
    const float* X = (const float*)d_in[0];
    const float* U = (const float*)d_in[1];
    const float* S = (const float*)d_in[2];
    const float* V = (const float*)d_in[3];
    float* Out = (float*)d_out;

    float* H = (float*)d_ws;                              // 1 MB fp32
    __hip_bfloat16* Hpart = (__hip_bfloat16*)((float*)d_ws + 262144);  // 4 MB bf16

    if (ws_size >= (size_t)5 * 1024 * 1024) {             // proven-available branch
        // 2048 blocks = TRUE 8 blocks/CU (32 waves/CU)
        lora_h<<<dim3(256, 8), 256, 0, stream>>>(X, V, Hpart);
        lora_hred<8><<<256, 256, 0, stream>>>((const ushort*)Hpart, S, H);
        lora_out<<<1024, 256, 0, stream>>>(H, U, Out);
    } else {
        lora_h_naive<<<1024, 256, 0, stream>>>(X, S, V, H);
        lora_out<<<1024, 256, 0, stream>>>(H, U, Out);
    }
}